// Round 13
// baseline (580.003 us; speedup 1.0000x reference)
//
#include <hip/hip_runtime.h>
#include <hip/hip_bf16.h>

#define NN 100000
#define NE 3200000
#define NG 1000
#define BN_EPS 1e-5f

#define BKT_SH 6            // 64 nodes per bucket
#define BKTN 64
#define NBKT 1563           // ceil(NN/64)
#define CHUNK 2048          // edges per bin_kernel block (small -> high occupancy)
#define NBINBLK 1563        // ceil(NE/CHUNK)

typedef __attribute__((ext_vector_type(8))) short short8v;
typedef __attribute__((ext_vector_type(4))) float f32x4;

__device__ __forceinline__ unsigned int f2bf(float f) {
    unsigned int u = __builtin_bit_cast(unsigned int, f);
    u += 0x7FFFu + ((u >> 16) & 1u);        // round-to-nearest-even
    return u >> 16;
}
__device__ __forceinline__ float bf2f(unsigned int h16) {
    return __builtin_bit_cast(float, h16 << 16);
}

// ---------------- prep: pack x + weight transpose + bucket histogram ----------------
__global__ void prep_kernel(const float* __restrict__ x, unsigned int* __restrict__ xp,
                            const float* __restrict__ W1a, const float* __restrict__ W1b,
                            const float* __restrict__ W2a, const float* __restrict__ W2b,
                            unsigned int* __restrict__ Wt,
                            const int* __restrict__ dst, int* __restrict__ bcnt) {
    __shared__ int h[NBKT];
    int bx = blockIdx.x;
    int t = threadIdx.x;
    if (bx < 25000) {
        int tid = bx * 256 + t;                  // NN*64 exact
        float2 v = ((const float2*)x)[tid];
        xp[tid] = f2bf(v.x) | (f2bf(v.y) << 16);
    } else if (bx < 25128) {
        int tid = (bx - 25000) * 256 + t;        // 4*128*64 = 32768
        int m = tid >> 13;
        int r = tid & 8191;
        int c = r >> 6, kh = r & 63;
        const float* W = (m == 0) ? W1a : (m == 1) ? W1b : (m == 2) ? W2a : W2b;
        float a = W[(2 * kh) * 128 + c];
        float b = W[(2 * kh + 1) * 128 + c];
        Wt[tid] = f2bf(a) | (f2bf(b) << 16);
    } else {
        int blk = bx - 25128;                    // 0..NBINBLK-1
        for (int i = t; i < NBKT; i += 256) h[i] = 0;
        __syncthreads();
        int c0 = blk * CHUNK;
        int cnt = min(CHUNK, NE - c0);
        for (int i = t; i < cnt; i += 256) atomicAdd(&h[dst[c0 + i] >> BKT_SH], 1);
        __syncthreads();
        for (int i = t; i < NBKT; i += 256) if (h[i]) atomicAdd(&bcnt[i], h[i]);
    }
}

// ---------------- exclusive scan of bucket counts ----------------
__global__ void bucket_scan_kernel(const int* __restrict__ bcnt, int* __restrict__ bbase,
                                   int* __restrict__ bcur) {
    __shared__ int wsum[16];
    __shared__ int lcarry;
    int t = threadIdx.x, lane = t & 63, w = t >> 6;
    if (t == 0) lcarry = 0;
    __syncthreads();
    for (int base = 0; base < NBKT; base += 1024) {
        int i = base + t;
        int v = (i < NBKT) ? bcnt[i] : 0;
        int incl = v;
        #pragma unroll
        for (int d = 1; d < 64; d <<= 1) { int u = __shfl_up(incl, d, 64); if (lane >= d) incl += u; }
        if (lane == 63) wsum[w] = incl;
        __syncthreads();
        if (w == 0) {
            int s = (lane < 16) ? wsum[lane] : 0;
            #pragma unroll
            for (int d = 1; d < 16; d <<= 1) { int u = __shfl_up(s, d, 64); if (lane >= d) s += u; }
            if (lane < 16) wsum[lane] = s;
        }
        __syncthreads();
        int excl = lcarry + (w ? wsum[w - 1] : 0) + incl - v;
        if (i < NBKT) { bbase[i] = excl; bcur[i] = excl; }
        __syncthreads();
        if (t == 0) lcarry += wsum[15];
        __syncthreads();
    }
}

// ---------------- binning: direct scatter to bucket regions (high occupancy) ----------------
__global__ __launch_bounds__(256) void bin_kernel(const int* __restrict__ src,
        const int* __restrict__ dst, int* __restrict__ bcur,
        unsigned int* __restrict__ ebin) {
    __shared__ int hist[NBKT];
    __shared__ int delta[NBKT];
    __shared__ int lcur[NBKT];
    int t = threadIdx.x;
    int c0 = blockIdx.x * CHUNK;
    int cnt = min(CHUNK, NE - c0);
    for (int i = t; i < NBKT; i += 256) { hist[i] = 0; lcur[i] = 0; }
    __syncthreads();
    for (int i = t; i < cnt; i += 256) atomicAdd(&hist[dst[c0 + i] >> BKT_SH], 1);
    __syncthreads();
    for (int b = t; b < NBKT; b += 256) {
        int hh = hist[b];
        delta[b] = hh ? atomicAdd(&bcur[b], hh) : 0;
    }
    __syncthreads();
    for (int i = t; i < cnt; i += 256) {
        int d = dst[c0 + i];
        int s = src[c0 + i];
        int b = d >> BKT_SH;
        int p = atomicAdd(&lcur[b], 1);
        ebin[delta[b] + p] = ((unsigned int)s << BKT_SH) | (unsigned int)(d & (BKTN - 1));
    }
}

// ---------------- per-bucket counting sort -> per-node CSR ----------------
__global__ __launch_bounds__(256) void sort_kernel(const unsigned int* __restrict__ ebin,
        const int* __restrict__ bbase, const int* __restrict__ bcnt,
        int* __restrict__ noffs, int* __restrict__ csrc) {
    __shared__ int nh[BKTN], ncur[BKTN];
    int b = blockIdx.x, t = threadIdx.x;
    int base = bbase[b], cnt = bcnt[b];
    if (t < BKTN) nh[t] = 0;
    __syncthreads();
    for (int i = t; i < cnt; i += 256) atomicAdd(&nh[ebin[base + i] & (BKTN - 1)], 1);
    __syncthreads();
    if (t < 64) {
        int v = nh[t], incl = v;
        #pragma unroll
        for (int d = 1; d < 64; d <<= 1) { int u = __shfl_up(incl, d, 64); if (t >= d) incl += u; }
        int excl = incl - v;
        ncur[t] = excl;
        int node = (b << BKT_SH) + t;
        if (node < NN) noffs[node] = base + excl;
    }
    if (b == 0 && t == 0) noffs[NN] = NE;
    __syncthreads();
    for (int i = t; i < cnt; i += 256) {
        unsigned int e = ebin[base + i];
        int p = atomicAdd(&ncur[e & (BKTN - 1)], 1);
        csrc[base + p] = (int)(e >> BKT_SH);
    }
}

// ---------------- aggregation: one wave per node, ILP-16; BN_IN applies relu(h*a+b) ----------------
template<int BN_IN>
__global__ __launch_bounds__(256) void aggregate_gather_kernel(
        const unsigned int* __restrict__ xp, const float* __restrict__ coef,
        const int* __restrict__ noffs, const int* __restrict__ csrc,
        unsigned int* __restrict__ outp) {
    int node = __builtin_amdgcn_readfirstlane(blockIdx.x * 4 + (threadIdx.x >> 6));
    int lane = threadIdx.x & 63;
    float a0 = 1.f, b0 = 0.f, a1 = 1.f, b1 = 0.f;
    if (BN_IN) {
        float2 av = ((const float2*)coef)[lane];
        float2 bv = ((const float2*)(coef + 128))[lane];
        a0 = av.x; a1 = av.y; b0 = bv.x; b1 = bv.y;
    }
    unsigned int u = xp[(size_t)node * 64 + lane];
    float alo = bf2f(u & 0xFFFFu), ahi = bf2f(u >> 16);
    if (BN_IN) { alo = fmaxf(alo * a0 + b0, 0.f); ahi = fmaxf(ahi * a1 + b1, 0.f); }
    int s = noffs[node], e = noffs[node + 1];
    int i = s;
    for (; i + 16 <= e; i += 16) {
        int idx[16];
        #pragma unroll
        for (int j = 0; j < 16; ++j) idx[j] = csrc[i + j];
        unsigned int uv[16];
        #pragma unroll
        for (int j = 0; j < 16; ++j) uv[j] = xp[(size_t)idx[j] * 64 + lane];
        #pragma unroll
        for (int j = 0; j < 16; ++j) {
            float lo = bf2f(uv[j] & 0xFFFFu), hi = bf2f(uv[j] >> 16);
            if (BN_IN) { lo = fmaxf(lo * a0 + b0, 0.f); hi = fmaxf(hi * a1 + b1, 0.f); }
            alo += lo; ahi += hi;
        }
    }
    for (; i + 8 <= e; i += 8) {
        int idx[8];
        #pragma unroll
        for (int j = 0; j < 8; ++j) idx[j] = csrc[i + j];
        unsigned int uv[8];
        #pragma unroll
        for (int j = 0; j < 8; ++j) uv[j] = xp[(size_t)idx[j] * 64 + lane];
        #pragma unroll
        for (int j = 0; j < 8; ++j) {
            float lo = bf2f(uv[j] & 0xFFFFu), hi = bf2f(uv[j] >> 16);
            if (BN_IN) { lo = fmaxf(lo * a0 + b0, 0.f); hi = fmaxf(hi * a1 + b1, 0.f); }
            alo += lo; ahi += hi;
        }
    }
    for (; i < e; ++i) {
        int sv = csrc[i];
        unsigned int uu = xp[(size_t)sv * 64 + lane];
        float lo = bf2f(uu & 0xFFFFu), hi = bf2f(uu >> 16);
        if (BN_IN) { lo = fmaxf(lo * a0 + b0, 0.f); hi = fmaxf(hi * a1 + b1, 0.f); }
        alo += lo; ahi += hi;
    }
    outp[(size_t)node * 64 + lane] = f2bf(alo) | (f2bf(ahi) << 16);
}

// ---------------- fused MLP + BN stats: H2=(relu(H0@Wa+ba))@Wb+bb; per-block channel partials ----------------
__global__ __launch_bounds__(256) void mlp_kernel(const unsigned int* __restrict__ Pin,
        const unsigned int* __restrict__ WtA, const float* __restrict__ bA,
        const unsigned int* __restrict__ WtB, const float* __restrict__ bB,
        unsigned int* __restrict__ Pout, float* __restrict__ partial) {
    __shared__ unsigned int tile[64 * 68];      // 17.4 KB
    __shared__ float sred[4][128];
    __shared__ float qred[4][128];
    int t = threadIdx.x, l = t & 63, w = t >> 6;
    int node0 = blockIdx.x * 64;
    int rbase = w * 16;
    int g = l >> 4, r = l & 15;
    int g4 = g * 4;

    const uint4* P4 = (const uint4*)Pin;
    #pragma unroll
    for (int i = 0; i < 4; ++i) {
        int rl = rbase + i * 4 + g;
        int node = node0 + rl;
        uint4 v = make_uint4(0u, 0u, 0u, 0u);
        if (node < NN) v = P4[(size_t)node * 16 + r];
        *(uint4*)&tile[rl * 68 + r * 4] = v;
    }
    // no barrier: each wave reads only its own rows

    f32x4 acc1[8];
    #pragma unroll
    for (int cb = 0; cb < 8; ++cb) acc1[cb] = (f32x4){0.f, 0.f, 0.f, 0.f};
    #pragma unroll
    for (int kk = 0; kk < 4; ++kk) {
        short8v a = *(short8v*)&tile[(rbase + r) * 68 + kk * 16 + g4];
        #pragma unroll
        for (int cb = 0; cb < 8; ++cb) {
            short8v wv = *(const short8v*)&WtA[(size_t)(cb * 16 + r) * 64 + kk * 16 + g4];
            acc1[cb] = __builtin_amdgcn_mfma_f32_16x16x32_bf16(wv, a, acc1[cb], 0, 0, 0);
        }
    }
    #pragma unroll
    for (int cb = 0; cb < 8; ++cb) {
        int c0 = cb * 16 + g4;
        float4 bi = *(const float4*)&bA[c0];
        float h0 = fmaxf(acc1[cb][0] + bi.x, 0.f);
        float h1 = fmaxf(acc1[cb][1] + bi.y, 0.f);
        float h2 = fmaxf(acc1[cb][2] + bi.z, 0.f);
        float h3 = fmaxf(acc1[cb][3] + bi.w, 0.f);
        uint2 pk;
        pk.x = f2bf(h0) | (f2bf(h1) << 16);
        pk.y = f2bf(h2) | (f2bf(h3) << 16);
        *(uint2*)&tile[(rbase + r) * 68 + (c0 >> 1)] = pk;
    }
    f32x4 acc2[8];
    #pragma unroll
    for (int cb = 0; cb < 8; ++cb) acc2[cb] = (f32x4){0.f, 0.f, 0.f, 0.f};
    #pragma unroll
    for (int kk = 0; kk < 4; ++kk) {
        short8v a = *(short8v*)&tile[(rbase + r) * 68 + kk * 16 + g4];
        #pragma unroll
        for (int cb = 0; cb < 8; ++cb) {
            short8v wv = *(const short8v*)&WtB[(size_t)(cb * 16 + r) * 64 + kk * 16 + g4];
            acc2[cb] = __builtin_amdgcn_mfma_f32_16x16x32_bf16(wv, a, acc2[cb], 0, 0, 0);
        }
    }
    int node = node0 + rbase + r;
    bool valid = node < NN;
    float msk = valid ? 1.f : 0.f;
    #pragma unroll
    for (int cb = 0; cb < 8; ++cb) {
        int c0 = cb * 16 + g4;
        float4 bi = *(const float4*)&bB[c0];
        float h0 = acc2[cb][0] + bi.x;
        float h1 = acc2[cb][1] + bi.y;
        float h2 = acc2[cb][2] + bi.z;
        float h3 = acc2[cb][3] + bi.w;
        // BN partial: reduce over the 16 r-lanes (nodes) of this wave
        float s0 = h0 * msk, s1 = h1 * msk, s2 = h2 * msk, s3 = h3 * msk;
        float q0 = s0 * h0, q1 = s1 * h1, q2 = s2 * h2, q3 = s3 * h3;
        #pragma unroll
        for (int m = 1; m < 16; m <<= 1) {
            s0 += __shfl_xor(s0, m, 64); s1 += __shfl_xor(s1, m, 64);
            s2 += __shfl_xor(s2, m, 64); s3 += __shfl_xor(s3, m, 64);
            q0 += __shfl_xor(q0, m, 64); q1 += __shfl_xor(q1, m, 64);
            q2 += __shfl_xor(q2, m, 64); q3 += __shfl_xor(q3, m, 64);
        }
        if (r == 0) {
            sred[w][c0 + 0] = s0; sred[w][c0 + 1] = s1;
            sred[w][c0 + 2] = s2; sred[w][c0 + 3] = s3;
            qred[w][c0 + 0] = q0; qred[w][c0 + 1] = q1;
            qred[w][c0 + 2] = q2; qred[w][c0 + 3] = q3;
        }
        if (valid) {
            uint2 pk;
            pk.x = f2bf(h0) | (f2bf(h1) << 16);
            pk.y = f2bf(h2) | (f2bf(h3) << 16);
            *(uint2*)&Pout[(size_t)node * 64 + (c0 >> 1)] = pk;
        }
    }
    __syncthreads();
    if (t < 128) {
        partial[(size_t)blockIdx.x * 256 + t] =
            sred[0][t] + sred[1][t] + sred[2][t] + sred[3][t];
    } else {
        int c = t - 128;
        partial[(size_t)blockIdx.x * 256 + t] =
            qred[0][c] + qred[1][c] + qred[2][c] + qred[3][c];
    }
}

// ---------------- BN stats reduce: one block per channel ----------------
__global__ __launch_bounds__(256) void bn_reduce_kernel(const float* __restrict__ partial,
        const float* __restrict__ gamma, const float* __restrict__ beta,
        float* __restrict__ coef) {
    __shared__ float red[2][256];
    int c = blockIdx.x;          // 0..127
    int t = threadIdx.x;         // 256
    float sm = 0.f, sq = 0.f;
    for (int i = t; i < NBKT; i += 256) {
        sm += partial[(size_t)i * 256 + c];
        sq += partial[(size_t)i * 256 + 128 + c];
    }
    red[0][t] = sm; red[1][t] = sq;
    __syncthreads();
    if (t < 64) {
        float s = red[0][t] + red[0][t + 64] + red[0][t + 128] + red[0][t + 192];
        float q = red[1][t] + red[1][t + 64] + red[1][t + 128] + red[1][t + 192];
        #pragma unroll
        for (int m = 1; m < 64; m <<= 1) {
            s += __shfl_xor(s, m, 64);
            q += __shfl_xor(q, m, 64);
        }
        if (t == 0) {
            const float inv = 1.0f / NN;
            float mean = s * inv;
            float var = q * inv - mean * mean;
            float a = gamma[c] * rsqrtf(var + BN_EPS);
            coef[c] = a;
            coef[128 + c] = beta[c] - mean * a;
        }
    }
}

// ---------------- fused pool + head: BN+relu on the fly, segment-sum, logits, log_softmax ----------------
__global__ void pool_head_kernel(const unsigned int* __restrict__ hb,
        const float* __restrict__ coef, const int* __restrict__ batch,
        const float* __restrict__ Wlin, const float* __restrict__ blin,
        float* __restrict__ out) {
    int g = blockIdx.x;
    int l = threadIdx.x;   // 64
    float2 av = ((const float2*)coef)[l];
    float2 bv = ((const float2*)(coef + 128))[l];
    int a = 0, b = NN;
    while (a < b) { int m = (a + b) >> 1; if (batch[m] < g) a = m + 1; else b = m; }
    int start = a;
    b = NN;
    while (a < b) { int m = (a + b) >> 1; if (batch[m] < g + 1) a = m + 1; else b = m; }
    int end = a;
    float s0 = 0.f, s1 = 0.f;
    for (int i = start; i < end; ++i) {
        unsigned int u = hb[(size_t)i * 64 + l];
        s0 += fmaxf(bf2f(u & 0xFFFFu) * av.x + bv.x, 0.f);
        s1 += fmaxf(bf2f(u >> 16) * av.y + bv.y, 0.f);
    }
    float lg[10];
    #pragma unroll
    for (int o = 0; o < 10; ++o) {
        float partial = s0 * Wlin[(2 * l) * 10 + o] + s1 * Wlin[(2 * l + 1) * 10 + o];
        #pragma unroll
        for (int m = 1; m < 64; m <<= 1) partial += __shfl_xor(partial, m, 64);
        lg[o] = partial + blin[o];
    }
    float mx = lg[0];
    #pragma unroll
    for (int o = 1; o < 10; ++o) mx = fmaxf(mx, lg[o]);
    float se = 0.f;
    #pragma unroll
    for (int o = 0; o < 10; ++o) se += expf(lg[o] - mx);
    float lse = mx + logf(se);
    if (l == 0) {
        #pragma unroll
        for (int o = 0; o < 10; ++o) out[g * 10 + o] = lg[o] - lse;
    }
}

extern "C" void kernel_launch(void* const* d_in, const int* in_sizes, int n_in,
                              void* d_out, int out_size, void* d_ws, size_t ws_size,
                              hipStream_t stream) {
    const float* x    = (const float*)d_in[0];
    const int*   edge = (const int*)d_in[1];   // [2][NE]
    const int*   batch= (const int*)d_in[2];
    const float* W1a  = (const float*)d_in[3];
    const float* b1a  = (const float*)d_in[4];
    const float* W1b  = (const float*)d_in[5];
    const float* b1b  = (const float*)d_in[6];
    const float* g1   = (const float*)d_in[7];
    const float* be1  = (const float*)d_in[8];
    const float* W2a  = (const float*)d_in[9];
    const float* b2a  = (const float*)d_in[10];
    const float* W2b  = (const float*)d_in[11];
    const float* b2b  = (const float*)d_in[12];
    const float* g2   = (const float*)d_in[13];
    const float* be2  = (const float*)d_in[14];
    const float* Wlin = (const float*)d_in[15];
    const float* blin = (const float*)d_in[16];
    float* out = (float*)d_out;

    char* ws = (char*)d_ws;
    size_t off = 0;
    auto alloc = [&](size_t bytes) -> void* {
        void* p = ws + off; off += (bytes + 255) & ~(size_t)255; return p;
    };
    unsigned int* Px   = (unsigned int*)alloc((size_t)NN * 64 * 4);
    unsigned int* Pa   = (unsigned int*)alloc((size_t)NN * 64 * 4);
    unsigned int* Pb   = (unsigned int*)alloc((size_t)NN * 64 * 4);
    unsigned int* ebin = (unsigned int*)alloc((size_t)NE * 4);
    int*   csrc   = (int*)alloc((size_t)NE * 4);
    int*   noffs  = (int*)alloc((NN + 1) * 4);
    int*   bcnt   = (int*)alloc(NBKT * 4);
    int*   bbase  = (int*)alloc(NBKT * 4);
    int*   bcur   = (int*)alloc(NBKT * 4);
    float* coef1  = (float*)alloc(256 * 4);
    float* coef2  = (float*)alloc(256 * 4);
    float* partial= (float*)alloc((size_t)NBKT * 256 * 4);
    unsigned int* Wt = (unsigned int*)alloc(4 * 8192 * 4);
    unsigned int* Wt1a = Wt;
    unsigned int* Wt1b = Wt + 8192;
    unsigned int* Wt2a = Wt + 16384;
    unsigned int* Wt2b = Wt + 24576;

    const int* srcI = edge;
    const int* dstI = edge + NE;

    hipMemsetAsync(bcnt, 0, NBKT * 4, stream);

    prep_kernel<<<25128 + NBINBLK, 256, 0, stream>>>(x, Px, W1a, W1b, W2a, W2b, Wt,
                                                     dstI, bcnt);
    bucket_scan_kernel<<<1, 1024, 0, stream>>>(bcnt, bbase, bcur);
    bin_kernel<<<NBINBLK, 256, 0, stream>>>(srcI, dstI, bcur, ebin);
    sort_kernel<<<NBKT, 256, 0, stream>>>(ebin, bbase, bcnt, noffs, csrc);

    // ---- layer 1 ----
    aggregate_gather_kernel<0><<<25000, 256, 0, stream>>>(Px, coef1, noffs, csrc, Pa);
    mlp_kernel<<<NBKT, 256, 0, stream>>>(Pa, Wt1a, b1a, Wt1b, b1b, Pb, partial);
    bn_reduce_kernel<<<128, 256, 0, stream>>>(partial, g1, be1, coef1);
    // ---- layer 2 ----
    aggregate_gather_kernel<1><<<25000, 256, 0, stream>>>(Pb, coef1, noffs, csrc, Pa);
    mlp_kernel<<<NBKT, 256, 0, stream>>>(Pa, Wt2a, b2a, Wt2b, b2b, Pb, partial);
    bn_reduce_kernel<<<128, 256, 0, stream>>>(partial, g2, be2, coef2);

    pool_head_kernel<<<NG, 64, 0, stream>>>(Pb, coef2, batch, Wlin, blin, out);
}

// Round 14
// 534.515 us; speedup vs baseline: 1.0851x; 1.0851x over previous
//
#include <hip/hip_runtime.h>
#include <hip/hip_bf16.h>

#define NN 100000
#define NE 3200000
#define NG 1000
#define BN_EPS 1e-5f

#define BKT_SH 7            // 128 nodes per binning bucket
#define BKTN 128
#define NBKT 782            // ceil(NN/128)
#define CHUNK 4096          // edges per bin_kernel block
#define NBINBLK 782         // ceil(NE/CHUNK)
#define HCHUNK 2048         // edges per histogram chunk
#define NHBLK 1563          // ceil(NE/HCHUNK)
#define NTILE 1563          // 64-node tiles for mlp grid / partials

typedef __attribute__((ext_vector_type(8))) short short8v;
typedef __attribute__((ext_vector_type(4))) float f32x4;

__device__ __forceinline__ unsigned int f2bf(float f) {
    unsigned int u = __builtin_bit_cast(unsigned int, f);
    u += 0x7FFFu + ((u >> 16) & 1u);        // round-to-nearest-even
    return u >> 16;
}
__device__ __forceinline__ float bf2f(unsigned int h16) {
    return __builtin_bit_cast(float, h16 << 16);
}

// ---------------- prep: pack x + weight transpose + bucket histogram ----------------
__global__ void prep_kernel(const float* __restrict__ x, unsigned int* __restrict__ xp,
                            const float* __restrict__ W1a, const float* __restrict__ W1b,
                            const float* __restrict__ W2a, const float* __restrict__ W2b,
                            unsigned int* __restrict__ Wt,
                            const int* __restrict__ dst, int* __restrict__ bcnt) {
    __shared__ int h[NBKT];
    int bx = blockIdx.x;
    int t = threadIdx.x;
    if (bx < 25000) {
        int tid = bx * 256 + t;                  // NN*64 exact
        float2 v = ((const float2*)x)[tid];
        xp[tid] = f2bf(v.x) | (f2bf(v.y) << 16);
    } else if (bx < 25128) {
        int tid = (bx - 25000) * 256 + t;        // 4*128*64 = 32768
        int m = tid >> 13;
        int r = tid & 8191;
        int c = r >> 6, kh = r & 63;
        const float* W = (m == 0) ? W1a : (m == 1) ? W1b : (m == 2) ? W2a : W2b;
        float a = W[(2 * kh) * 128 + c];
        float b = W[(2 * kh + 1) * 128 + c];
        Wt[tid] = f2bf(a) | (f2bf(b) << 16);
    } else {
        int blk = bx - 25128;                    // 0..NHBLK-1
        for (int i = t; i < NBKT; i += 256) h[i] = 0;
        __syncthreads();
        int c0 = blk * HCHUNK;
        int cnt = min(HCHUNK, NE - c0);
        for (int i = t; i < cnt; i += 256) atomicAdd(&h[dst[c0 + i] >> BKT_SH], 1);
        __syncthreads();
        for (int i = t; i < NBKT; i += 256) if (h[i]) atomicAdd(&bcnt[i], h[i]);
    }
}

// ---------------- exclusive scan of bucket counts (782 <= 1024) ----------------
__global__ void bucket_scan_kernel(const int* __restrict__ bcnt, int* __restrict__ bbase,
                                   int* __restrict__ bcur) {
    __shared__ int wsum[16];
    int t = threadIdx.x, lane = t & 63, w = t >> 6;
    int v = (t < NBKT) ? bcnt[t] : 0;
    int incl = v;
    #pragma unroll
    for (int d = 1; d < 64; d <<= 1) { int u = __shfl_up(incl, d, 64); if (lane >= d) incl += u; }
    if (lane == 63) wsum[w] = incl;
    __syncthreads();
    if (w == 0) {
        int s = (lane < 16) ? wsum[lane] : 0;
        #pragma unroll
        for (int d = 1; d < 16; d <<= 1) { int u = __shfl_up(s, d, 64); if (lane >= d) s += u; }
        if (lane < 16) wsum[lane] = s;
    }
    __syncthreads();
    int excl = (w ? wsum[w - 1] : 0) + incl - v;
    if (t < NBKT) { bbase[t] = excl; bcur[t] = excl; }
}

// ---------------- binning: staged by 128-node bucket (CHUNK=4096, 782 blocks) ----------------
__global__ __launch_bounds__(256) void bin_kernel(const int* __restrict__ src,
        const int* __restrict__ dst, int* __restrict__ bcur,
        unsigned int* __restrict__ ebin) {
    __shared__ unsigned int ebuf[CHUNK];        // 16 KB
    __shared__ unsigned short bids[CHUNK];      // 8 KB
    __shared__ int hist[NBKT], lbase[NBKT], lcur[NBKT], delta[NBKT];   // 12.5 KB
    __shared__ int wsum4[4];
    __shared__ int carry;
    int t = threadIdx.x;
    int lane = t & 63, w = t >> 6;
    int c0 = blockIdx.x * CHUNK;
    int cnt = min(CHUNK, NE - c0);
    for (int i = t; i < NBKT; i += 256) hist[i] = 0;
    if (t == 0) carry = 0;
    __syncthreads();
    for (int i = t; i < cnt; i += 256) atomicAdd(&hist[dst[c0 + i] >> BKT_SH], 1);
    __syncthreads();
    for (int bb = 0; bb < NBKT; bb += 256) {
        int i = bb + t;
        int v = (i < NBKT) ? hist[i] : 0;
        int incl = v;
        #pragma unroll
        for (int d2 = 1; d2 < 64; d2 <<= 1) { int u = __shfl_up(incl, d2, 64); if (lane >= d2) incl += u; }
        if (lane == 63) wsum4[w] = incl;
        __syncthreads();
        int wo = 0;
        if (w > 0) wo = wsum4[0];
        if (w > 1) wo += wsum4[1];
        if (w > 2) wo += wsum4[2];
        int excl = carry + wo + incl - v;
        if (i < NBKT) { lbase[i] = excl; lcur[i] = excl; }
        int tot = wsum4[0] + wsum4[1] + wsum4[2] + wsum4[3];
        __syncthreads();
        if (t == 0) carry += tot;
        __syncthreads();
    }
    for (int b = t; b < NBKT; b += 256) {
        int hh = hist[b];
        delta[b] = (hh ? atomicAdd(&bcur[b], hh) : 0) - lbase[b];
    }
    __syncthreads();
    for (int i = t; i < cnt; i += 256) {
        int d = dst[c0 + i];
        int s = src[c0 + i];
        int b = d >> BKT_SH;
        unsigned int entry = ((unsigned int)s << BKT_SH) | (unsigned int)(d & (BKTN - 1));
        int p = atomicAdd(&lcur[b], 1);
        ebuf[p] = entry;
        bids[p] = (unsigned short)b;
    }
    __syncthreads();
    for (int i = t; i < cnt; i += 256) {
        ebin[delta[bids[i]] + i] = ebuf[i];
    }
}

// ---------------- per-bucket counting sort (128 nodes/bucket) -> per-node CSR ----------------
__global__ __launch_bounds__(256) void sort_kernel(const unsigned int* __restrict__ ebin,
        const int* __restrict__ bbase, const int* __restrict__ bcnt,
        int* __restrict__ noffs, int* __restrict__ csrc) {
    __shared__ int nh[BKTN], nbase[BKTN], ncur[BKTN];
    int b = blockIdx.x, t = threadIdx.x;
    int base = bbase[b], cnt = bcnt[b];
    if (t < BKTN) nh[t] = 0;
    __syncthreads();
    for (int i = t; i < cnt; i += 256) atomicAdd(&nh[ebin[base + i] & (BKTN - 1)], 1);
    __syncthreads();
    if (t < 64) {
        int v0 = nh[t], v1 = nh[64 + t];
        int i0 = v0;
        #pragma unroll
        for (int d = 1; d < 64; d <<= 1) { int u = __shfl_up(i0, d, 64); if (t >= d) i0 += u; }
        int tot0 = __shfl(i0, 63, 64);
        int i1 = v1;
        #pragma unroll
        for (int d = 1; d < 64; d <<= 1) { int u = __shfl_up(i1, d, 64); if (t >= d) i1 += u; }
        int e0 = i0 - v0;
        int e1 = tot0 + i1 - v1;
        nbase[t] = e0; nbase[64 + t] = e1;
        ncur[t] = e0; ncur[64 + t] = e1;
        int node0 = (b << BKT_SH) + t;
        int node1 = node0 + 64;
        if (node0 < NN) noffs[node0] = base + e0;
        if (node1 < NN) noffs[node1] = base + e1;
    }
    if (b == 0 && t == 0) noffs[NN] = NE;
    __syncthreads();
    for (int i = t; i < cnt; i += 256) {
        unsigned int e = ebin[base + i];
        int p = atomicAdd(&ncur[e & (BKTN - 1)], 1);
        csrc[base + p] = (int)(e >> BKT_SH);
    }
}

// ---------------- aggregation: one wave per node, ILP-16; BN_IN applies relu(h*a+b) ----------------
template<int BN_IN>
__global__ __launch_bounds__(256) void aggregate_gather_kernel(
        const unsigned int* __restrict__ xp, const float* __restrict__ coef,
        const int* __restrict__ noffs, const int* __restrict__ csrc,
        unsigned int* __restrict__ outp) {
    int node = __builtin_amdgcn_readfirstlane(blockIdx.x * 4 + (threadIdx.x >> 6));
    int lane = threadIdx.x & 63;
    float a0 = 1.f, b0 = 0.f, a1 = 1.f, b1 = 0.f;
    if (BN_IN) {
        float2 av = ((const float2*)coef)[lane];
        float2 bv = ((const float2*)(coef + 128))[lane];
        a0 = av.x; a1 = av.y; b0 = bv.x; b1 = bv.y;
    }
    unsigned int u = xp[(size_t)node * 64 + lane];
    float alo = bf2f(u & 0xFFFFu), ahi = bf2f(u >> 16);
    if (BN_IN) { alo = fmaxf(alo * a0 + b0, 0.f); ahi = fmaxf(ahi * a1 + b1, 0.f); }
    int s = noffs[node], e = noffs[node + 1];
    int i = s;
    for (; i + 16 <= e; i += 16) {
        int idx[16];
        #pragma unroll
        for (int j = 0; j < 16; ++j) idx[j] = csrc[i + j];
        unsigned int uv[16];
        #pragma unroll
        for (int j = 0; j < 16; ++j) uv[j] = xp[(size_t)idx[j] * 64 + lane];
        #pragma unroll
        for (int j = 0; j < 16; ++j) {
            float lo = bf2f(uv[j] & 0xFFFFu), hi = bf2f(uv[j] >> 16);
            if (BN_IN) { lo = fmaxf(lo * a0 + b0, 0.f); hi = fmaxf(hi * a1 + b1, 0.f); }
            alo += lo; ahi += hi;
        }
    }
    for (; i + 8 <= e; i += 8) {
        int idx[8];
        #pragma unroll
        for (int j = 0; j < 8; ++j) idx[j] = csrc[i + j];
        unsigned int uv[8];
        #pragma unroll
        for (int j = 0; j < 8; ++j) uv[j] = xp[(size_t)idx[j] * 64 + lane];
        #pragma unroll
        for (int j = 0; j < 8; ++j) {
            float lo = bf2f(uv[j] & 0xFFFFu), hi = bf2f(uv[j] >> 16);
            if (BN_IN) { lo = fmaxf(lo * a0 + b0, 0.f); hi = fmaxf(hi * a1 + b1, 0.f); }
            alo += lo; ahi += hi;
        }
    }
    for (; i < e; ++i) {
        int sv = csrc[i];
        unsigned int uu = xp[(size_t)sv * 64 + lane];
        float lo = bf2f(uu & 0xFFFFu), hi = bf2f(uu >> 16);
        if (BN_IN) { lo = fmaxf(lo * a0 + b0, 0.f); hi = fmaxf(hi * a1 + b1, 0.f); }
        alo += lo; ahi += hi;
    }
    outp[(size_t)node * 64 + lane] = f2bf(alo) | (f2bf(ahi) << 16);
}

// ---------------- fused MLP + BN stats: H2=(relu(H0@Wa+ba))@Wb+bb; per-block channel partials ----------------
__global__ __launch_bounds__(256) void mlp_kernel(const unsigned int* __restrict__ Pin,
        const unsigned int* __restrict__ WtA, const float* __restrict__ bA,
        const unsigned int* __restrict__ WtB, const float* __restrict__ bB,
        unsigned int* __restrict__ Pout, float* __restrict__ partial) {
    __shared__ unsigned int tile[64 * 68];      // 17.4 KB
    __shared__ float sred[4][128];
    __shared__ float qred[4][128];
    int t = threadIdx.x, l = t & 63, w = t >> 6;
    int node0 = blockIdx.x * 64;
    int rbase = w * 16;
    int g = l >> 4, r = l & 15;
    int g4 = g * 4;

    const uint4* P4 = (const uint4*)Pin;
    #pragma unroll
    for (int i = 0; i < 4; ++i) {
        int rl = rbase + i * 4 + g;
        int node = node0 + rl;
        uint4 v = make_uint4(0u, 0u, 0u, 0u);
        if (node < NN) v = P4[(size_t)node * 16 + r];
        *(uint4*)&tile[rl * 68 + r * 4] = v;
    }
    // no barrier: each wave reads only its own rows

    f32x4 acc1[8];
    #pragma unroll
    for (int cb = 0; cb < 8; ++cb) acc1[cb] = (f32x4){0.f, 0.f, 0.f, 0.f};
    #pragma unroll
    for (int kk = 0; kk < 4; ++kk) {
        short8v a = *(short8v*)&tile[(rbase + r) * 68 + kk * 16 + g4];
        #pragma unroll
        for (int cb = 0; cb < 8; ++cb) {
            short8v wv = *(const short8v*)&WtA[(size_t)(cb * 16 + r) * 64 + kk * 16 + g4];
            acc1[cb] = __builtin_amdgcn_mfma_f32_16x16x32_bf16(wv, a, acc1[cb], 0, 0, 0);
        }
    }
    #pragma unroll
    for (int cb = 0; cb < 8; ++cb) {
        int c0 = cb * 16 + g4;
        float4 bi = *(const float4*)&bA[c0];
        float h0 = fmaxf(acc1[cb][0] + bi.x, 0.f);
        float h1 = fmaxf(acc1[cb][1] + bi.y, 0.f);
        float h2 = fmaxf(acc1[cb][2] + bi.z, 0.f);
        float h3 = fmaxf(acc1[cb][3] + bi.w, 0.f);
        uint2 pk;
        pk.x = f2bf(h0) | (f2bf(h1) << 16);
        pk.y = f2bf(h2) | (f2bf(h3) << 16);
        *(uint2*)&tile[(rbase + r) * 68 + (c0 >> 1)] = pk;
    }
    f32x4 acc2[8];
    #pragma unroll
    for (int cb = 0; cb < 8; ++cb) acc2[cb] = (f32x4){0.f, 0.f, 0.f, 0.f};
    #pragma unroll
    for (int kk = 0; kk < 4; ++kk) {
        short8v a = *(short8v*)&tile[(rbase + r) * 68 + kk * 16 + g4];
        #pragma unroll
        for (int cb = 0; cb < 8; ++cb) {
            short8v wv = *(const short8v*)&WtB[(size_t)(cb * 16 + r) * 64 + kk * 16 + g4];
            acc2[cb] = __builtin_amdgcn_mfma_f32_16x16x32_bf16(wv, a, acc2[cb], 0, 0, 0);
        }
    }
    int node = node0 + rbase + r;
    bool valid = node < NN;
    float msk = valid ? 1.f : 0.f;
    #pragma unroll
    for (int cb = 0; cb < 8; ++cb) {
        int c0 = cb * 16 + g4;
        float4 bi = *(const float4*)&bB[c0];
        float h0 = acc2[cb][0] + bi.x;
        float h1 = acc2[cb][1] + bi.y;
        float h2 = acc2[cb][2] + bi.z;
        float h3 = acc2[cb][3] + bi.w;
        // BN partial: reduce over the 16 r-lanes (nodes) of this wave
        float s0 = h0 * msk, s1 = h1 * msk, s2 = h2 * msk, s3 = h3 * msk;
        float q0 = s0 * h0, q1 = s1 * h1, q2 = s2 * h2, q3 = s3 * h3;
        #pragma unroll
        for (int m = 1; m < 16; m <<= 1) {
            s0 += __shfl_xor(s0, m, 64); s1 += __shfl_xor(s1, m, 64);
            s2 += __shfl_xor(s2, m, 64); s3 += __shfl_xor(s3, m, 64);
            q0 += __shfl_xor(q0, m, 64); q1 += __shfl_xor(q1, m, 64);
            q2 += __shfl_xor(q2, m, 64); q3 += __shfl_xor(q3, m, 64);
        }
        if (r == 0) {
            sred[w][c0 + 0] = s0; sred[w][c0 + 1] = s1;
            sred[w][c0 + 2] = s2; sred[w][c0 + 3] = s3;
            qred[w][c0 + 0] = q0; qred[w][c0 + 1] = q1;
            qred[w][c0 + 2] = q2; qred[w][c0 + 3] = q3;
        }
        if (valid) {
            uint2 pk;
            pk.x = f2bf(h0) | (f2bf(h1) << 16);
            pk.y = f2bf(h2) | (f2bf(h3) << 16);
            *(uint2*)&Pout[(size_t)node * 64 + (c0 >> 1)] = pk;
        }
    }
    __syncthreads();
    if (t < 128) {
        partial[(size_t)blockIdx.x * 256 + t] =
            sred[0][t] + sred[1][t] + sred[2][t] + sred[3][t];
    } else {
        int c = t - 128;
        partial[(size_t)blockIdx.x * 256 + t] =
            qred[0][c] + qred[1][c] + qred[2][c] + qred[3][c];
    }
}

// ---------------- BN stats reduce: one block per channel ----------------
__global__ __launch_bounds__(256) void bn_reduce_kernel(const float* __restrict__ partial,
        const float* __restrict__ gamma, const float* __restrict__ beta,
        float* __restrict__ coef) {
    __shared__ float red[2][256];
    int c = blockIdx.x;          // 0..127
    int t = threadIdx.x;         // 256
    float sm = 0.f, sq = 0.f;
    for (int i = t; i < NTILE; i += 256) {
        sm += partial[(size_t)i * 256 + c];
        sq += partial[(size_t)i * 256 + 128 + c];
    }
    red[0][t] = sm; red[1][t] = sq;
    __syncthreads();
    if (t < 64) {
        float s = red[0][t] + red[0][t + 64] + red[0][t + 128] + red[0][t + 192];
        float q = red[1][t] + red[1][t + 64] + red[1][t + 128] + red[1][t + 192];
        #pragma unroll
        for (int m = 1; m < 64; m <<= 1) {
            s += __shfl_xor(s, m, 64);
            q += __shfl_xor(q, m, 64);
        }
        if (t == 0) {
            const float inv = 1.0f / NN;
            float mean = s * inv;
            float var = q * inv - mean * mean;
            float a = gamma[c] * rsqrtf(var + BN_EPS);
            coef[c] = a;
            coef[128 + c] = beta[c] - mean * a;
        }
    }
}

// ---------------- fused pool + head: BN+relu on the fly, segment-sum, logits, log_softmax ----------------
__global__ void pool_head_kernel(const unsigned int* __restrict__ hb,
        const float* __restrict__ coef, const int* __restrict__ batch,
        const float* __restrict__ Wlin, const float* __restrict__ blin,
        float* __restrict__ out) {
    int g = blockIdx.x;
    int l = threadIdx.x;   // 64
    float2 av = ((const float2*)coef)[l];
    float2 bv = ((const float2*)(coef + 128))[l];
    int a = 0, b = NN;
    while (a < b) { int m = (a + b) >> 1; if (batch[m] < g) a = m + 1; else b = m; }
    int start = a;
    b = NN;
    while (a < b) { int m = (a + b) >> 1; if (batch[m] < g + 1) a = m + 1; else b = m; }
    int end = a;
    float s0 = 0.f, s1 = 0.f;
    for (int i = start; i < end; ++i) {
        unsigned int u = hb[(size_t)i * 64 + l];
        s0 += fmaxf(bf2f(u & 0xFFFFu) * av.x + bv.x, 0.f);
        s1 += fmaxf(bf2f(u >> 16) * av.y + bv.y, 0.f);
    }
    float lg[10];
    #pragma unroll
    for (int o = 0; o < 10; ++o) {
        float partial = s0 * Wlin[(2 * l) * 10 + o] + s1 * Wlin[(2 * l + 1) * 10 + o];
        #pragma unroll
        for (int m = 1; m < 64; m <<= 1) partial += __shfl_xor(partial, m, 64);
        lg[o] = partial + blin[o];
    }
    float mx = lg[0];
    #pragma unroll
    for (int o = 1; o < 10; ++o) mx = fmaxf(mx, lg[o]);
    float se = 0.f;
    #pragma unroll
    for (int o = 0; o < 10; ++o) se += expf(lg[o] - mx);
    float lse = mx + logf(se);
    if (l == 0) {
        #pragma unroll
        for (int o = 0; o < 10; ++o) out[g * 10 + o] = lg[o] - lse;
    }
}

extern "C" void kernel_launch(void* const* d_in, const int* in_sizes, int n_in,
                              void* d_out, int out_size, void* d_ws, size_t ws_size,
                              hipStream_t stream) {
    const float* x    = (const float*)d_in[0];
    const int*   edge = (const int*)d_in[1];   // [2][NE]
    const int*   batch= (const int*)d_in[2];
    const float* W1a  = (const float*)d_in[3];
    const float* b1a  = (const float*)d_in[4];
    const float* W1b  = (const float*)d_in[5];
    const float* b1b  = (const float*)d_in[6];
    const float* g1   = (const float*)d_in[7];
    const float* be1  = (const float*)d_in[8];
    const float* W2a  = (const float*)d_in[9];
    const float* b2a  = (const float*)d_in[10];
    const float* W2b  = (const float*)d_in[11];
    const float* b2b  = (const float*)d_in[12];
    const float* g2   = (const float*)d_in[13];
    const float* be2  = (const float*)d_in[14];
    const float* Wlin = (const float*)d_in[15];
    const float* blin = (const float*)d_in[16];
    float* out = (float*)d_out;

    char* ws = (char*)d_ws;
    size_t off = 0;
    auto alloc = [&](size_t bytes) -> void* {
        void* p = ws + off; off += (bytes + 255) & ~(size_t)255; return p;
    };
    unsigned int* Px   = (unsigned int*)alloc((size_t)NN * 64 * 4);
    unsigned int* Pa   = (unsigned int*)alloc((size_t)NN * 64 * 4);
    unsigned int* Pb   = (unsigned int*)alloc((size_t)NN * 64 * 4);
    unsigned int* ebin = (unsigned int*)alloc((size_t)NE * 4);
    int*   csrc   = (int*)alloc((size_t)NE * 4);
    int*   noffs  = (int*)alloc((NN + 1) * 4);
    int*   bcnt   = (int*)alloc(NBKT * 4);
    int*   bbase  = (int*)alloc(NBKT * 4);
    int*   bcur   = (int*)alloc(NBKT * 4);
    float* coef1  = (float*)alloc(256 * 4);
    float* coef2  = (float*)alloc(256 * 4);
    float* partial= (float*)alloc((size_t)NTILE * 256 * 4);
    unsigned int* Wt = (unsigned int*)alloc(4 * 8192 * 4);
    unsigned int* Wt1a = Wt;
    unsigned int* Wt1b = Wt + 8192;
    unsigned int* Wt2a = Wt + 16384;
    unsigned int* Wt2b = Wt + 24576;

    const int* srcI = edge;
    const int* dstI = edge + NE;

    hipMemsetAsync(bcnt, 0, NBKT * 4, stream);

    prep_kernel<<<25128 + NHBLK, 256, 0, stream>>>(x, Px, W1a, W1b, W2a, W2b, Wt,
                                                   dstI, bcnt);
    bucket_scan_kernel<<<1, 1024, 0, stream>>>(bcnt, bbase, bcur);
    bin_kernel<<<NBINBLK, 256, 0, stream>>>(srcI, dstI, bcur, ebin);
    sort_kernel<<<NBKT, 256, 0, stream>>>(ebin, bbase, bcnt, noffs, csrc);

    // ---- layer 1 ----
    aggregate_gather_kernel<0><<<25000, 256, 0, stream>>>(Px, coef1, noffs, csrc, Pa);
    mlp_kernel<<<NTILE, 256, 0, stream>>>(Pa, Wt1a, b1a, Wt1b, b1b, Pb, partial);
    bn_reduce_kernel<<<128, 256, 0, stream>>>(partial, g1, be1, coef1);
    // ---- layer 2 ----
    aggregate_gather_kernel<1><<<25000, 256, 0, stream>>>(Pb, coef1, noffs, csrc, Pa);
    mlp_kernel<<<NTILE, 256, 0, stream>>>(Pa, Wt2a, b2a, Wt2b, b2b, Pb, partial);
    bn_reduce_kernel<<<128, 256, 0, stream>>>(partial, g2, be2, coef2);

    pool_head_kernel<<<NG, 64, 0, stream>>>(Pb, coef2, batch, Wlin, blin, out);
}

// Round 15
// 507.623 us; speedup vs baseline: 1.1426x; 1.0530x over previous
//
#include <hip/hip_runtime.h>
#include <hip/hip_bf16.h>

#define NN 100000
#define NE 3200000
#define NG 1000
#define BN_EPS 1e-5f

#define BKT_SH 6            // 64 nodes per bucket
#define BKTN 64
#define NBKT 1563           // ceil(NN/64)
#define CHUNK 8192          // edges per bin_kernel block
#define NBINBLK 391         // ceil(NE/CHUNK)

typedef __attribute__((ext_vector_type(8))) short short8v;
typedef __attribute__((ext_vector_type(4))) float f32x4;

__device__ __forceinline__ unsigned int f2bf(float f) {
    unsigned int u = __builtin_bit_cast(unsigned int, f);
    u += 0x7FFFu + ((u >> 16) & 1u);        // round-to-nearest-even
    return u >> 16;
}
__device__ __forceinline__ float bf2f(unsigned int h16) {
    return __builtin_bit_cast(float, h16 << 16);
}

// ---------------- prep: pack x + weight transpose + bucket histogram ----------------
__global__ void prep_kernel(const float* __restrict__ x, unsigned int* __restrict__ xp,
                            const float* __restrict__ W1a, const float* __restrict__ W1b,
                            const float* __restrict__ W2a, const float* __restrict__ W2b,
                            unsigned int* __restrict__ Wt,
                            const int* __restrict__ dst, int* __restrict__ bcnt) {
    __shared__ int h[NBKT];
    int bx = blockIdx.x;
    int t = threadIdx.x;
    if (bx < 25000) {
        int tid = bx * 256 + t;                  // NN*64 exact
        float2 v = ((const float2*)x)[tid];
        xp[tid] = f2bf(v.x) | (f2bf(v.y) << 16);
    } else if (bx < 25128) {
        int tid = (bx - 25000) * 256 + t;        // 4*128*64 = 32768
        int m = tid >> 13;
        int r = tid & 8191;
        int c = r >> 6, kh = r & 63;
        const float* W = (m == 0) ? W1a : (m == 1) ? W1b : (m == 2) ? W2a : W2b;
        float a = W[(2 * kh) * 128 + c];
        float b = W[(2 * kh + 1) * 128 + c];
        Wt[tid] = f2bf(a) | (f2bf(b) << 16);
    } else {
        int blk = bx - 25128;                    // 0..NBINBLK-1
        for (int i = t; i < NBKT; i += 256) h[i] = 0;
        __syncthreads();
        int c0 = blk * CHUNK;
        int cnt = min(CHUNK, NE - c0);
        for (int i = t; i < cnt; i += 256) atomicAdd(&h[dst[c0 + i] >> BKT_SH], 1);
        __syncthreads();
        for (int i = t; i < NBKT; i += 256) if (h[i]) atomicAdd(&bcnt[i], h[i]);
    }
}

// ---------------- exclusive scan of bucket counts ----------------
__global__ void bucket_scan_kernel(const int* __restrict__ bcnt, int* __restrict__ bbase,
                                   int* __restrict__ bcur) {
    __shared__ int wsum[16];
    __shared__ int lcarry;
    int t = threadIdx.x, lane = t & 63, w = t >> 6;
    if (t == 0) lcarry = 0;
    __syncthreads();
    for (int base = 0; base < NBKT; base += 1024) {
        int i = base + t;
        int v = (i < NBKT) ? bcnt[i] : 0;
        int incl = v;
        #pragma unroll
        for (int d = 1; d < 64; d <<= 1) { int u = __shfl_up(incl, d, 64); if (lane >= d) incl += u; }
        if (lane == 63) wsum[w] = incl;
        __syncthreads();
        if (w == 0) {
            int s = (lane < 16) ? wsum[lane] : 0;
            #pragma unroll
            for (int d = 1; d < 16; d <<= 1) { int u = __shfl_up(s, d, 64); if (lane >= d) s += u; }
            if (lane < 16) wsum[lane] = s;
        }
        __syncthreads();
        int excl = lcarry + (w ? wsum[w - 1] : 0) + incl - v;
        if (i < NBKT) { bbase[i] = excl; bcur[i] = excl; }
        __syncthreads();
        if (t == 0) lcarry += wsum[15];
        __syncthreads();
    }
}

// ---------------- binning: staged group-by-bucket (CHUNK=8192, 391 blocks) ----------------
__global__ __launch_bounds__(256) void bin_kernel(const int* __restrict__ src,
        const int* __restrict__ dst, int* __restrict__ bcur,
        unsigned int* __restrict__ ebin) {
    __shared__ unsigned int ebuf[CHUNK];        // 32 KB
    __shared__ unsigned short bids[CHUNK];      // 16 KB
    __shared__ int hist[NBKT], lbase[NBKT], lcur[NBKT], delta[NBKT];   // 25 KB
    __shared__ int wsum4[4];
    __shared__ int carry;
    int t = threadIdx.x;
    int lane = t & 63, w = t >> 6;
    int c0 = blockIdx.x * CHUNK;
    int cnt = min(CHUNK, NE - c0);
    for (int i = t; i < NBKT; i += 256) hist[i] = 0;
    if (t == 0) carry = 0;
    __syncthreads();
    for (int i = t; i < cnt; i += 256) atomicAdd(&hist[dst[c0 + i] >> BKT_SH], 1);
    __syncthreads();
    for (int bb = 0; bb < NBKT; bb += 256) {
        int i = bb + t;
        int v = (i < NBKT) ? hist[i] : 0;
        int incl = v;
        #pragma unroll
        for (int d2 = 1; d2 < 64; d2 <<= 1) { int u = __shfl_up(incl, d2, 64); if (lane >= d2) incl += u; }
        if (lane == 63) wsum4[w] = incl;
        __syncthreads();
        int wo = 0;
        if (w > 0) wo = wsum4[0];
        if (w > 1) wo += wsum4[1];
        if (w > 2) wo += wsum4[2];
        int excl = carry + wo + incl - v;
        if (i < NBKT) { lbase[i] = excl; lcur[i] = excl; }
        int tot = wsum4[0] + wsum4[1] + wsum4[2] + wsum4[3];
        __syncthreads();
        if (t == 0) carry += tot;
        __syncthreads();
    }
    for (int b = t; b < NBKT; b += 256) {
        int hh = hist[b];
        delta[b] = (hh ? atomicAdd(&bcur[b], hh) : 0) - lbase[b];
    }
    __syncthreads();
    for (int i = t; i < cnt; i += 256) {
        int d = dst[c0 + i];
        int s = src[c0 + i];
        int b = d >> BKT_SH;
        unsigned int entry = ((unsigned int)s << BKT_SH) | (unsigned int)(d & (BKTN - 1));
        int p = atomicAdd(&lcur[b], 1);
        ebuf[p] = entry;
        bids[p] = (unsigned short)b;
    }
    __syncthreads();
    for (int i = t; i < cnt; i += 256) {
        ebin[delta[bids[i]] + i] = ebuf[i];
    }
}

// ---------------- per-bucket counting sort -> per-node CSR ----------------
__global__ __launch_bounds__(256) void sort_kernel(const unsigned int* __restrict__ ebin,
        const int* __restrict__ bbase, const int* __restrict__ bcnt,
        int* __restrict__ noffs, int* __restrict__ csrc) {
    __shared__ int nh[BKTN], ncur[BKTN];
    int b = blockIdx.x, t = threadIdx.x;
    int base = bbase[b], cnt = bcnt[b];
    if (t < BKTN) nh[t] = 0;
    __syncthreads();
    for (int i = t; i < cnt; i += 256) atomicAdd(&nh[ebin[base + i] & (BKTN - 1)], 1);
    __syncthreads();
    if (t < 64) {
        int v = nh[t], incl = v;
        #pragma unroll
        for (int d = 1; d < 64; d <<= 1) { int u = __shfl_up(incl, d, 64); if (t >= d) incl += u; }
        int excl = incl - v;
        ncur[t] = excl;
        int node = (b << BKT_SH) + t;
        if (node < NN) noffs[node] = base + excl;
    }
    if (b == 0 && t == 0) noffs[NN] = NE;
    __syncthreads();
    for (int i = t; i < cnt; i += 256) {
        unsigned int e = ebin[base + i];
        int p = atomicAdd(&ncur[e & (BKTN - 1)], 1);
        csrc[base + p] = (int)(e >> BKT_SH);
    }
}

// ---------------- aggregation: one wave per node, ILP-16; BN_IN applies relu(h*a+b) ----------------
template<int BN_IN>
__global__ __launch_bounds__(256) void aggregate_gather_kernel(
        const unsigned int* __restrict__ xp, const float* __restrict__ coef,
        const int* __restrict__ noffs, const int* __restrict__ csrc,
        unsigned int* __restrict__ outp) {
    int node = __builtin_amdgcn_readfirstlane(blockIdx.x * 4 + (threadIdx.x >> 6));
    int lane = threadIdx.x & 63;
    float a0 = 1.f, b0 = 0.f, a1 = 1.f, b1 = 0.f;
    if (BN_IN) {
        float2 av = ((const float2*)coef)[lane];
        float2 bv = ((const float2*)(coef + 128))[lane];
        a0 = av.x; a1 = av.y; b0 = bv.x; b1 = bv.y;
    }
    unsigned int u = xp[(size_t)node * 64 + lane];
    float alo = bf2f(u & 0xFFFFu), ahi = bf2f(u >> 16);
    if (BN_IN) { alo = fmaxf(alo * a0 + b0, 0.f); ahi = fmaxf(ahi * a1 + b1, 0.f); }
    int s = noffs[node], e = noffs[node + 1];
    int i = s;
    for (; i + 16 <= e; i += 16) {
        int idx[16];
        #pragma unroll
        for (int j = 0; j < 16; ++j) idx[j] = csrc[i + j];
        unsigned int uv[16];
        #pragma unroll
        for (int j = 0; j < 16; ++j) uv[j] = xp[(size_t)idx[j] * 64 + lane];
        #pragma unroll
        for (int j = 0; j < 16; ++j) {
            float lo = bf2f(uv[j] & 0xFFFFu), hi = bf2f(uv[j] >> 16);
            if (BN_IN) { lo = fmaxf(lo * a0 + b0, 0.f); hi = fmaxf(hi * a1 + b1, 0.f); }
            alo += lo; ahi += hi;
        }
    }
    for (; i + 8 <= e; i += 8) {
        int idx[8];
        #pragma unroll
        for (int j = 0; j < 8; ++j) idx[j] = csrc[i + j];
        unsigned int uv[8];
        #pragma unroll
        for (int j = 0; j < 8; ++j) uv[j] = xp[(size_t)idx[j] * 64 + lane];
        #pragma unroll
        for (int j = 0; j < 8; ++j) {
            float lo = bf2f(uv[j] & 0xFFFFu), hi = bf2f(uv[j] >> 16);
            if (BN_IN) { lo = fmaxf(lo * a0 + b0, 0.f); hi = fmaxf(hi * a1 + b1, 0.f); }
            alo += lo; ahi += hi;
        }
    }
    for (; i < e; ++i) {
        int sv = csrc[i];
        unsigned int uu = xp[(size_t)sv * 64 + lane];
        float lo = bf2f(uu & 0xFFFFu), hi = bf2f(uu >> 16);
        if (BN_IN) { lo = fmaxf(lo * a0 + b0, 0.f); hi = fmaxf(hi * a1 + b1, 0.f); }
        alo += lo; ahi += hi;
    }
    outp[(size_t)node * 64 + lane] = f2bf(alo) | (f2bf(ahi) << 16);
}

// ---------------- fused MLP + BN stats: H2=(relu(H0@Wa+ba))@Wb+bb; per-block channel partials ----------------
__global__ __launch_bounds__(256) void mlp_kernel(const unsigned int* __restrict__ Pin,
        const unsigned int* __restrict__ WtA, const float* __restrict__ bA,
        const unsigned int* __restrict__ WtB, const float* __restrict__ bB,
        unsigned int* __restrict__ Pout, float* __restrict__ partial) {
    __shared__ unsigned int tile[64 * 68];      // 17.4 KB
    __shared__ float sred[4][128];
    __shared__ float qred[4][128];
    int t = threadIdx.x, l = t & 63, w = t >> 6;
    int node0 = blockIdx.x * 64;
    int rbase = w * 16;
    int g = l >> 4, r = l & 15;
    int g4 = g * 4;

    const uint4* P4 = (const uint4*)Pin;
    #pragma unroll
    for (int i = 0; i < 4; ++i) {
        int rl = rbase + i * 4 + g;
        int node = node0 + rl;
        uint4 v = make_uint4(0u, 0u, 0u, 0u);
        if (node < NN) v = P4[(size_t)node * 16 + r];
        *(uint4*)&tile[rl * 68 + r * 4] = v;
    }
    // no barrier: each wave reads only its own rows

    f32x4 acc1[8];
    #pragma unroll
    for (int cb = 0; cb < 8; ++cb) acc1[cb] = (f32x4){0.f, 0.f, 0.f, 0.f};
    #pragma unroll
    for (int kk = 0; kk < 4; ++kk) {
        short8v a = *(short8v*)&tile[(rbase + r) * 68 + kk * 16 + g4];
        #pragma unroll
        for (int cb = 0; cb < 8; ++cb) {
            short8v wv = *(const short8v*)&WtA[(size_t)(cb * 16 + r) * 64 + kk * 16 + g4];
            acc1[cb] = __builtin_amdgcn_mfma_f32_16x16x32_bf16(wv, a, acc1[cb], 0, 0, 0);
        }
    }
    #pragma unroll
    for (int cb = 0; cb < 8; ++cb) {
        int c0 = cb * 16 + g4;
        float4 bi = *(const float4*)&bA[c0];
        float h0 = fmaxf(acc1[cb][0] + bi.x, 0.f);
        float h1 = fmaxf(acc1[cb][1] + bi.y, 0.f);
        float h2 = fmaxf(acc1[cb][2] + bi.z, 0.f);
        float h3 = fmaxf(acc1[cb][3] + bi.w, 0.f);
        uint2 pk;
        pk.x = f2bf(h0) | (f2bf(h1) << 16);
        pk.y = f2bf(h2) | (f2bf(h3) << 16);
        *(uint2*)&tile[(rbase + r) * 68 + (c0 >> 1)] = pk;
    }
    f32x4 acc2[8];
    #pragma unroll
    for (int cb = 0; cb < 8; ++cb) acc2[cb] = (f32x4){0.f, 0.f, 0.f, 0.f};
    #pragma unroll
    for (int kk = 0; kk < 4; ++kk) {
        short8v a = *(short8v*)&tile[(rbase + r) * 68 + kk * 16 + g4];
        #pragma unroll
        for (int cb = 0; cb < 8; ++cb) {
            short8v wv = *(const short8v*)&WtB[(size_t)(cb * 16 + r) * 64 + kk * 16 + g4];
            acc2[cb] = __builtin_amdgcn_mfma_f32_16x16x32_bf16(wv, a, acc2[cb], 0, 0, 0);
        }
    }
    int node = node0 + rbase + r;
    bool valid = node < NN;
    float msk = valid ? 1.f : 0.f;
    #pragma unroll
    for (int cb = 0; cb < 8; ++cb) {
        int c0 = cb * 16 + g4;
        float4 bi = *(const float4*)&bB[c0];
        float h0 = acc2[cb][0] + bi.x;
        float h1 = acc2[cb][1] + bi.y;
        float h2 = acc2[cb][2] + bi.z;
        float h3 = acc2[cb][3] + bi.w;
        // BN partial: reduce over the 16 r-lanes (nodes) of this wave
        float s0 = h0 * msk, s1 = h1 * msk, s2 = h2 * msk, s3 = h3 * msk;
        float q0 = s0 * h0, q1 = s1 * h1, q2 = s2 * h2, q3 = s3 * h3;
        #pragma unroll
        for (int m = 1; m < 16; m <<= 1) {
            s0 += __shfl_xor(s0, m, 64); s1 += __shfl_xor(s1, m, 64);
            s2 += __shfl_xor(s2, m, 64); s3 += __shfl_xor(s3, m, 64);
            q0 += __shfl_xor(q0, m, 64); q1 += __shfl_xor(q1, m, 64);
            q2 += __shfl_xor(q2, m, 64); q3 += __shfl_xor(q3, m, 64);
        }
        if (r == 0) {
            sred[w][c0 + 0] = s0; sred[w][c0 + 1] = s1;
            sred[w][c0 + 2] = s2; sred[w][c0 + 3] = s3;
            qred[w][c0 + 0] = q0; qred[w][c0 + 1] = q1;
            qred[w][c0 + 2] = q2; qred[w][c0 + 3] = q3;
        }
        if (valid) {
            uint2 pk;
            pk.x = f2bf(h0) | (f2bf(h1) << 16);
            pk.y = f2bf(h2) | (f2bf(h3) << 16);
            *(uint2*)&Pout[(size_t)node * 64 + (c0 >> 1)] = pk;
        }
    }
    __syncthreads();
    if (t < 128) {
        partial[(size_t)blockIdx.x * 256 + t] =
            sred[0][t] + sred[1][t] + sred[2][t] + sred[3][t];
    } else {
        int c = t - 128;
        partial[(size_t)blockIdx.x * 256 + t] =
            qred[0][c] + qred[1][c] + qred[2][c] + qred[3][c];
    }
}

// ---------------- BN stats reduce: one block per channel ----------------
__global__ __launch_bounds__(256) void bn_reduce_kernel(const float* __restrict__ partial,
        const float* __restrict__ gamma, const float* __restrict__ beta,
        float* __restrict__ coef) {
    __shared__ float red[2][256];
    int c = blockIdx.x;          // 0..127
    int t = threadIdx.x;         // 256
    float sm = 0.f, sq = 0.f;
    for (int i = t; i < NBKT; i += 256) {
        sm += partial[(size_t)i * 256 + c];
        sq += partial[(size_t)i * 256 + 128 + c];
    }
    red[0][t] = sm; red[1][t] = sq;
    __syncthreads();
    if (t < 64) {
        float s = red[0][t] + red[0][t + 64] + red[0][t + 128] + red[0][t + 192];
        float q = red[1][t] + red[1][t + 64] + red[1][t + 128] + red[1][t + 192];
        #pragma unroll
        for (int m = 1; m < 64; m <<= 1) {
            s += __shfl_xor(s, m, 64);
            q += __shfl_xor(q, m, 64);
        }
        if (t == 0) {
            const float inv = 1.0f / NN;
            float mean = s * inv;
            float var = q * inv - mean * mean;
            float a = gamma[c] * rsqrtf(var + BN_EPS);
            coef[c] = a;
            coef[128 + c] = beta[c] - mean * a;
        }
    }
}

// ---------------- fused pool + head: BN+relu on the fly, segment-sum, logits, log_softmax ----------------
__global__ void pool_head_kernel(const unsigned int* __restrict__ hb,
        const float* __restrict__ coef, const int* __restrict__ batch,
        const float* __restrict__ Wlin, const float* __restrict__ blin,
        float* __restrict__ out) {
    int g = blockIdx.x;
    int l = threadIdx.x;   // 64
    float2 av = ((const float2*)coef)[l];
    float2 bv = ((const float2*)(coef + 128))[l];
    int a = 0, b = NN;
    while (a < b) { int m = (a + b) >> 1; if (batch[m] < g) a = m + 1; else b = m; }
    int start = a;
    b = NN;
    while (a < b) { int m = (a + b) >> 1; if (batch[m] < g + 1) a = m + 1; else b = m; }
    int end = a;
    float s0 = 0.f, s1 = 0.f;
    for (int i = start; i < end; ++i) {
        unsigned int u = hb[(size_t)i * 64 + l];
        s0 += fmaxf(bf2f(u & 0xFFFFu) * av.x + bv.x, 0.f);
        s1 += fmaxf(bf2f(u >> 16) * av.y + bv.y, 0.f);
    }
    float lg[10];
    #pragma unroll
    for (int o = 0; o < 10; ++o) {
        float partial = s0 * Wlin[(2 * l) * 10 + o] + s1 * Wlin[(2 * l + 1) * 10 + o];
        #pragma unroll
        for (int m = 1; m < 64; m <<= 1) partial += __shfl_xor(partial, m, 64);
        lg[o] = partial + blin[o];
    }
    float mx = lg[0];
    #pragma unroll
    for (int o = 1; o < 10; ++o) mx = fmaxf(mx, lg[o]);
    float se = 0.f;
    #pragma unroll
    for (int o = 0; o < 10; ++o) se += expf(lg[o] - mx);
    float lse = mx + logf(se);
    if (l == 0) {
        #pragma unroll
        for (int o = 0; o < 10; ++o) out[g * 10 + o] = lg[o] - lse;
    }
}

extern "C" void kernel_launch(void* const* d_in, const int* in_sizes, int n_in,
                              void* d_out, int out_size, void* d_ws, size_t ws_size,
                              hipStream_t stream) {
    const float* x    = (const float*)d_in[0];
    const int*   edge = (const int*)d_in[1];   // [2][NE]
    const int*   batch= (const int*)d_in[2];
    const float* W1a  = (const float*)d_in[3];
    const float* b1a  = (const float*)d_in[4];
    const float* W1b  = (const float*)d_in[5];
    const float* b1b  = (const float*)d_in[6];
    const float* g1   = (const float*)d_in[7];
    const float* be1  = (const float*)d_in[8];
    const float* W2a  = (const float*)d_in[9];
    const float* b2a  = (const float*)d_in[10];
    const float* W2b  = (const float*)d_in[11];
    const float* b2b  = (const float*)d_in[12];
    const float* g2   = (const float*)d_in[13];
    const float* be2  = (const float*)d_in[14];
    const float* Wlin = (const float*)d_in[15];
    const float* blin = (const float*)d_in[16];
    float* out = (float*)d_out;

    char* ws = (char*)d_ws;
    size_t off = 0;
    auto alloc = [&](size_t bytes) -> void* {
        void* p = ws + off; off += (bytes + 255) & ~(size_t)255; return p;
    };
    unsigned int* Px   = (unsigned int*)alloc((size_t)NN * 64 * 4);
    unsigned int* Pa   = (unsigned int*)alloc((size_t)NN * 64 * 4);
    unsigned int* Pb   = (unsigned int*)alloc((size_t)NN * 64 * 4);
    unsigned int* ebin = (unsigned int*)alloc((size_t)NE * 4);
    int*   csrc   = (int*)alloc((size_t)NE * 4);
    int*   noffs  = (int*)alloc((NN + 1) * 4);
    int*   bcnt   = (int*)alloc(NBKT * 4);
    int*   bbase  = (int*)alloc(NBKT * 4);
    int*   bcur   = (int*)alloc(NBKT * 4);
    float* coef1  = (float*)alloc(256 * 4);
    float* coef2  = (float*)alloc(256 * 4);
    float* partial= (float*)alloc((size_t)NBKT * 256 * 4);
    unsigned int* Wt = (unsigned int*)alloc(4 * 8192 * 4);
    unsigned int* Wt1a = Wt;
    unsigned int* Wt1b = Wt + 8192;
    unsigned int* Wt2a = Wt + 16384;
    unsigned int* Wt2b = Wt + 24576;

    const int* srcI = edge;
    const int* dstI = edge + NE;

    hipMemsetAsync(bcnt, 0, NBKT * 4, stream);

    prep_kernel<<<25128 + NBINBLK, 256, 0, stream>>>(x, Px, W1a, W1b, W2a, W2b, Wt,
                                                     dstI, bcnt);
    bucket_scan_kernel<<<1, 1024, 0, stream>>>(bcnt, bbase, bcur);
    bin_kernel<<<NBINBLK, 256, 0, stream>>>(srcI, dstI, bcur, ebin);
    sort_kernel<<<NBKT, 256, 0, stream>>>(ebin, bbase, bcnt, noffs, csrc);

    // ---- layer 1 ----
    aggregate_gather_kernel<0><<<25000, 256, 0, stream>>>(Px, coef1, noffs, csrc, Pa);
    mlp_kernel<<<NBKT, 256, 0, stream>>>(Pa, Wt1a, b1a, Wt1b, b1b, Pb, partial);
    bn_reduce_kernel<<<128, 256, 0, stream>>>(partial, g1, be1, coef1);
    // ---- layer 2 ----
    aggregate_gather_kernel<1><<<25000, 256, 0, stream>>>(Pb, coef1, noffs, csrc, Pa);
    mlp_kernel<<<NBKT, 256, 0, stream>>>(Pa, Wt2a, b2a, Wt2b, b2b, Pb, partial);
    bn_reduce_kernel<<<128, 256, 0, stream>>>(partial, g2, be2, coef2);

    pool_head_kernel<<<NG, 64, 0, stream>>>(Pb, coef2, batch, Wlin, blin, out);
}